// Round 1
// baseline (1824.192 us; speedup 1.0000x reference)
//
#include <hip/hip_runtime.h>

#define N1 30
#define N2 60
#define T_STEPS 1024
#define BATCH 2048

// Broadcast lane l's value of v to all lanes (returns wave-uniform SGPR value).
__device__ __forceinline__ float lane_bcast(float v, int l) {
  return __int_as_float(__builtin_amdgcn_readlane(__float_as_int(v), l));
}

// tanh(x) = 1 - 2/(exp(2x)+1)  -- stable for large |x| (-> +-1), no NaN.
__device__ __forceinline__ float fast_tanh(float x) {
  float e = __expf(2.0f * x);                    // v_mul + v_exp_f32
  float r = __builtin_amdgcn_rcpf(e + 1.0f);     // v_rcp_f32
  return fmaf(-2.0f, r, 1.0f);
}

__global__ __launch_bounds__(256) void hrnn_kernel(
    const float* __restrict__ inp,     // (T, B, 1)
    const float* __restrict__ noise1,  // (T, B, N1)
    const float* __restrict__ noise2,  // (T, B, N2)
    const float* __restrict__ W11,     // (N1, N1)
    const float* __restrict__ W22,     // (N2, N2)
    const float* __restrict__ W21,     // (N2, N1)
    const float* __restrict__ W21m,    // (N2, N1)
    const float* __restrict__ Win,     // (N1, 1)
    const float* __restrict__ Wout,    // (1, N2)
    float* __restrict__ out)           // (T, B, 1)
{
  const int lane = threadIdx.x & 63;
  int b = blockIdx.x * 4 + (threadIdx.x >> 6);   // one wave per batch element
  b = __builtin_amdgcn_readfirstlane(b);          // make wave-uniformity visible

  // Clamp row index for inactive lanes (their results are never consumed).
  const int i1 = (lane < N1) ? lane : 0;
  const int i2 = (lane < N2) ? lane : 0;

  // Per-lane weight rows, loop-invariant across all T steps -> registers.
  float w11[N1], w21[N1], w22[N2];
#pragma unroll
  for (int j = 0; j < N1; ++j) w11[j] = W11[i1 * N1 + j];
#pragma unroll
  for (int j = 0; j < N1; ++j) w21[j] = W21[i2 * N1 + j] * W21m[i2 * N1 + j];
#pragma unroll
  for (int j = 0; j < N2; ++j) w22[j] = W22[i2 * N2 + j];
  const float win  = (lane < N1) ? Win[lane]  : 0.0f;
  const float wout = (lane < N2) ? Wout[lane] : 0.0f;  // =0 masks p3 reduce

  // States: lane j holds r1[j] (j<N1) and r2[j] (j<N2).
  float s1 = 0.0f, s2 = 0.0f;

  const long str1 = (long)BATCH * N1;
  const long str2 = (long)BATCH * N2;
  const float* n1p = noise1 + (long)b * N1 + i1;
  const float* n2p = noise2 + (long)b * N2 + i2;
  const float* xp  = inp + b;   // wave-uniform address -> s_load
  float*       yp  = out + b;

  // Software pipeline: preload step 0.
  float x_c  = *xp;
  float n1_c = *n1p;
  float n2_c = *n2p;

  for (int t = 0; t < T_STEPS; ++t) {
    // ---- issue next step's loads first (overlap with compute) ----
    const long adv = (t < T_STEPS - 1) ? 1 : 0;   // clamp last prefetch
    xp  += BATCH * adv;
    n1p += str1 * adv;
    n2p += str2 * adv;
    const float x_n  = *xp;
    const float n1_n = *n1p;
    const float n2_n = *n2p;

    // ---- phase 1: r1_new = tanh(W11 @ r1 + Win*x + n1) ----
    float a0 = fmaf(win, x_c, n1_c);
    float a1 = 0.0f;
#pragma unroll
    for (int j = 0; j < N1; j += 2) {
      a0 = fmaf(w11[j],     lane_bcast(s1, j),     a0);
      a1 = fmaf(w11[j + 1], lane_bcast(s1, j + 1), a1);
    }
    const float s1n = fast_tanh(a0 + a1);

    // ---- phase 2: r2_new = tanh(W22 @ r2 + W21m @ r1_new + n2) ----
    float c0 = n2_c, c1 = 0.0f, c2 = 0.0f, c3 = 0.0f;
#pragma unroll
    for (int j = 0; j < N1; j += 2) {
      c0 = fmaf(w21[j],     lane_bcast(s1n, j),     c0);
      c1 = fmaf(w21[j + 1], lane_bcast(s1n, j + 1), c1);
    }
#pragma unroll
    for (int j = 0; j < N2; j += 4) {
      c0 = fmaf(w22[j],     lane_bcast(s2, j),     c0);
      c1 = fmaf(w22[j + 1], lane_bcast(s2, j + 1), c1);
      c2 = fmaf(w22[j + 2], lane_bcast(s2, j + 2), c2);
      c3 = fmaf(w22[j + 3], lane_bcast(s2, j + 3), c3);
    }
    const float s2n = fast_tanh((c0 + c1) + (c2 + c3));

    // ---- phase 3: y = Wout . r2_new  (wout==0 for lanes >= N2) ----
    float p = wout * s2n;
#pragma unroll
    for (int off = 32; off; off >>= 1) p += __shfl_xor(p, off, 64);
    if (lane == 0) *yp = p;
    yp += BATCH;

    // rotate pipeline + state
    s1 = s1n; s2 = s2n;
    x_c = x_n; n1_c = n1_n; n2_c = n2_n;
  }
}

extern "C" void kernel_launch(void* const* d_in, const int* in_sizes, int n_in,
                              void* d_out, int out_size, void* d_ws, size_t ws_size,
                              hipStream_t stream) {
  const float* inp    = (const float*)d_in[0];
  const float* noise1 = (const float*)d_in[1];
  const float* noise2 = (const float*)d_in[2];
  const float* W11    = (const float*)d_in[3];
  const float* W22    = (const float*)d_in[4];
  const float* W21    = (const float*)d_in[5];
  const float* W21m   = (const float*)d_in[6];
  const float* Win    = (const float*)d_in[7];
  const float* Wout   = (const float*)d_in[8];
  float* out = (float*)d_out;

  dim3 grid(BATCH / 4);   // 512 blocks, 4 waves (4 batch elements) each
  dim3 block(256);
  hipLaunchKernelGGL(hrnn_kernel, grid, block, 0, stream,
                     inp, noise1, noise2, W11, W22, W21, W21m, Win, Wout, out);
}

// Round 2
// 1708.779 us; speedup vs baseline: 1.0675x; 1.0675x over previous
//
#include <hip/hip_runtime.h>

#define N1 30
#define N2 60
#define T_STEPS 1024
#define BATCH 2048

// Broadcast lane l's value of v to all lanes (returns wave-uniform SGPR value).
__device__ __forceinline__ float lane_bcast(float v, int l) {
  return __int_as_float(__builtin_amdgcn_readlane(__float_as_int(v), l));
}

// tanh(x) = 1 - 2/(exp(2x)+1)  -- stable for large |x| (-> +-1), no NaN.
__device__ __forceinline__ float fast_tanh(float x) {
  float e = __expf(2.0f * x);                    // v_mul + v_exp_f32
  float r = __builtin_amdgcn_rcpf(e + 1.0f);     // v_rcp_f32
  return fmaf(-2.0f, r, 1.0f);
}

// __launch_bounds__(256, 2): 2 waves/EU minimum -> VGPR cap 256. The grid
// (2048 waves / 256 CU) caps occupancy at 2 waves/SIMD anyway, so spending
// VGPRs up to 256 is free; we NEED ~150+ so the 120 weight floats stay
// register-resident for all 1024 steps (round 1: VGPR=80 -> per-step reloads).
__global__ __launch_bounds__(256, 2) void hrnn_kernel(
    const float* __restrict__ inp,     // (T, B, 1)
    const float* __restrict__ noise1,  // (T, B, N1)
    const float* __restrict__ noise2,  // (T, B, N2)
    const float* __restrict__ W11,     // (N1, N1)
    const float* __restrict__ W22,     // (N2, N2)
    const float* __restrict__ W21,     // (N2, N1)
    const float* __restrict__ W21m,    // (N2, N1)
    const float* __restrict__ Win,     // (N1, 1)
    const float* __restrict__ Wout,    // (1, N2)
    float* __restrict__ out)           // (T, B, 1)
{
  const int lane = threadIdx.x & 63;
  int b = blockIdx.x * 4 + (threadIdx.x >> 6);   // one wave per batch element
  b = __builtin_amdgcn_readfirstlane(b);          // wave-uniform

  // Clamp row index for inactive lanes (their results are never consumed).
  const int i1 = (lane < N1) ? lane : 0;
  const int i2 = (lane < N2) ? lane : 0;

  // Per-lane weight rows, loop-invariant across all T steps -> registers.
  float w11[N1], w21[N1], w22[N2];
#pragma unroll
  for (int j = 0; j < N1; ++j) w11[j] = W11[i1 * N1 + j];
#pragma unroll
  for (int j = 0; j < N1; ++j) w21[j] = W21[i2 * N1 + j] * W21m[i2 * N1 + j];
#pragma unroll
  for (int j = 0; j < N2; ++j) w22[j] = W22[i2 * N2 + j];
  const float win  = (lane < N1) ? Win[lane]  : 0.0f;
  const float wout = (lane < N2) ? Wout[lane] : 0.0f;  // =0 masks p3 reduce

  // States: lane j holds r1[j] (j<N1) and r2[j] (j<N2).
  float s1 = 0.0f, s2 = 0.0f;

  // 32-bit element indices (max byte offset 503 MB < 4 GB) bumped by
  // wave-uniform strides: 1 v_add_u32 per pointer per step.
  unsigned n1i = (unsigned)b * N1 + (unsigned)i1;
  unsigned n2i = (unsigned)b * N2 + (unsigned)i2;
  unsigned xi  = (unsigned)b;
  unsigned yi  = (unsigned)b;

  // Software pipeline: preload step 0.
  float x_c  = inp[xi];
  float n1_c = noise1[n1i];
  float n2_c = noise2[n2i];

  for (int t = 0; t < T_STEPS; ++t) {
    // ---- issue next step's loads first (overlap with compute) ----
    const unsigned adv = (t < T_STEPS - 1) ? 1u : 0u;   // clamp last prefetch
    xi  += BATCH * adv;
    n1i += (unsigned)(BATCH * N1) * adv;
    n2i += (unsigned)(BATCH * N2) * adv;
    const float x_n  = inp[xi];
    const float n1_n = noise1[n1i];
    const float n2_n = noise2[n2i];

    // ---- phase 1: r1_new = tanh(W11 @ r1 + Win*x + n1) ----
    float a0 = fmaf(win, x_c, n1_c);
    float a1 = 0.0f;
#pragma unroll
    for (int j = 0; j < N1; j += 2) {
      a0 = fmaf(w11[j],     lane_bcast(s1, j),     a0);
      a1 = fmaf(w11[j + 1], lane_bcast(s1, j + 1), a1);
    }
    const float s1n = fast_tanh(a0 + a1);

    // ---- phase 2: r2_new = tanh(W22 @ r2 + W21m @ r1_new + n2) ----
    float c0 = n2_c, c1 = 0.0f, c2 = 0.0f, c3 = 0.0f;
#pragma unroll
    for (int j = 0; j < N2; j += 4) {
      c0 = fmaf(w22[j],     lane_bcast(s2, j),     c0);
      c1 = fmaf(w22[j + 1], lane_bcast(s2, j + 1), c1);
      c2 = fmaf(w22[j + 2], lane_bcast(s2, j + 2), c2);
      c3 = fmaf(w22[j + 3], lane_bcast(s2, j + 3), c3);
    }
#pragma unroll
    for (int j = 0; j < N1; j += 2) {
      c0 = fmaf(w21[j],     lane_bcast(s1n, j),     c0);
      c1 = fmaf(w21[j + 1], lane_bcast(s1n, j + 1), c1);
    }
    const float s2n = fast_tanh((c0 + c1) + (c2 + c3));

    // ---- phase 3: y = Wout . r2_new  (wout==0 for lanes >= N2) ----
    float p = wout * s2n;
#pragma unroll
    for (int off = 32; off; off >>= 1) p += __shfl_xor(p, off, 64);
    if (lane == 0) out[yi] = p;
    yi += BATCH;

    // rotate pipeline + state
    s1 = s1n; s2 = s2n;
    x_c = x_n; n1_c = n1_n; n2_c = n2_n;
  }
}

extern "C" void kernel_launch(void* const* d_in, const int* in_sizes, int n_in,
                              void* d_out, int out_size, void* d_ws, size_t ws_size,
                              hipStream_t stream) {
  const float* inp    = (const float*)d_in[0];
  const float* noise1 = (const float*)d_in[1];
  const float* noise2 = (const float*)d_in[2];
  const float* W11    = (const float*)d_in[3];
  const float* W22    = (const float*)d_in[4];
  const float* W21    = (const float*)d_in[5];
  const float* W21m   = (const float*)d_in[6];
  const float* Win    = (const float*)d_in[7];
  const float* Wout   = (const float*)d_in[8];
  float* out = (float*)d_out;

  dim3 grid(BATCH / 4);   // 512 blocks, 4 waves (4 batch elements) each
  dim3 block(256);
  hipLaunchKernelGGL(hrnn_kernel, grid, block, 0, stream,
                     inp, noise1, noise2, W11, W22, W21, W21m, Win, Wout, out);
}